// Round 9
// baseline (340.367 us; speedup 1.0000x reference)
//
#include <hip/hip_runtime.h>

#define B_DIM   512
#define IN_DIM  65536
#define OUT_DIM 16384
#define K_DIM   32

typedef float nfloat4 __attribute__((ext_vector_type(4)));   // native vec for nontemporal builtins

static __device__ __forceinline__ unsigned short f2bf(float f) {
    unsigned u = __builtin_bit_cast(unsigned, f);
    unsigned r = (u + 0x7FFFu + ((u >> 16) & 1u)) >> 16;   // round-to-nearest-even
    return (unsigned short)r;
}

// ---------------------------------------------------------------------------
// Kernel 1: transpose + fp32->bf16 via LDS corner-turn.
// Block = 512 threads (8 waves), tile = 32 in-cols x all 512 b.
// READ: each thread owns one b-row, reads a FULL 128-B line — now via
// NONTEMPORAL loads (round-8 post-mortem): x is read exactly once and never
// again, but its 128 MiB of read-fills were allocating in L3 and evicting
// the just-written 64 MiB xT, pushing ~half of sparse_main's 512 MB gather
// stream out to HBM (FETCH_SIZE = 253 MB, HBM-only counter). nt loads keep
// x out of L3 so xT stays resident for the gather phase.
// WRITE: stage bf16 tile in LDS, each wave stores 4 complete 1-KiB xT rows
// (full-line, single-owner). xT writes stay NORMAL (we want them cached).
// ---------------------------------------------------------------------------
__global__ __launch_bounds__(512) void transpose_bf16_k(const float* __restrict__ x,
                                                        unsigned short* __restrict__ xT) {
    __shared__ unsigned short tile[32][512];   // 32 KiB
    const int c0 = blockIdx.x * 32;
    const int t  = threadIdx.x;                // = this thread's b row
    const nfloat4* p = (const nfloat4*)(x + (size_t)t * IN_DIM + c0);
    nfloat4 v[8];
    #pragma unroll
    for (int j = 0; j < 8; ++j) v[j] = __builtin_nontemporal_load(p + j);
    #pragma unroll
    for (int j = 0; j < 8; ++j) {
        tile[4*j+0][t] = f2bf(v[j].x);
        tile[4*j+1][t] = f2bf(v[j].y);
        tile[4*j+2][t] = f2bf(v[j].z);
        tile[4*j+3][t] = f2bf(v[j].w);
    }
    __syncthreads();

    // 8 waves x 4 rows each: wave w stores rows c = w*4..w*4+3 whole.
    const int wid  = t >> 6;
    const int lane = t & 63;
    #pragma unroll
    for (int r = 0; r < 4; ++r) {
        const int c = wid * 4 + r;
        const uint4 d = *(const uint4*)(&tile[c][lane * 8]);
        *(uint4*)(xT + (size_t)(c0 + c) * B_DIM + lane * 8) = d;
    }
}

// ---------------------------------------------------------------------------
// Kernel 2: main — UNCHANGED from rounds 7/8 (verified: 89-90 us, VGPR=64
// no spill, WRITE 36.9 MB clean). Block = 512 threads (8 waves), one output
// per wave, lane owns 8 b's -> one row-gather = ONE global_load_dwordx4
// (1 KiB/instr), two named batches of 4 uint4 (<=8 loads in flight).
// Known wall: 253 MB of the 512 MB gather stream served from HBM (FETCH is
// HBM-only) -> L3 non-residency of xT is this round's target.
// ---------------------------------------------------------------------------
#define SE 520   // epilogue LDS stride

__global__ __launch_bounds__(512, 4) void sparse_main(const unsigned short* __restrict__ xT,
                                                      const int*   __restrict__ idxp,
                                                      const float* __restrict__ wp,
                                                      const float* __restrict__ biasp,
                                                      float*       __restrict__ out) {
    __shared__ float lds[8][SE];
    const int o_blk = blockIdx.x * 8;
    const int t    = threadIdx.x;
    const int wid  = t >> 6;         // 0..7 = this wave's output
    const int lane = t & 63;
    const int b8   = lane * 8;       // this thread's 8 b's (ushort units)
    const int o    = o_blk + wid;

    // wave's 32 idx/w scalars in lanes 0..31 (lanes 32..63 duplicate)
    const int   iv = idxp[o * K_DIM + (lane & 31)];
    const float wv = wp  [o * K_DIM + (lane & 31)];

    const unsigned short* base = xT + b8;

    float4 accL = make_float4(0.f, 0.f, 0.f, 0.f);
    float4 accH = make_float4(0.f, 0.f, 0.f, 0.f);

    uint4 A0, A1, A2, A3, B0, B1, B2, B3;
    float wA0, wA1, wA2, wA3, wB0, wB1, wB2, wB3;

#define GLOAD(dst, wdst, kk) do { \
        const int si_ = __builtin_amdgcn_readlane(iv, (kk)); \
        wdst = __int_as_float(__builtin_amdgcn_readlane(__float_as_int(wv), (kk))); \
        dst = *(const uint4*)(base + ((size_t)si_ << 9)); \
    } while (0)

#define FMA8(u, sw) do { \
        accL.x = fmaf(sw, __int_as_float(u.x << 16),         accL.x); \
        accL.y = fmaf(sw, __int_as_float(u.x & 0xFFFF0000u), accL.y); \
        accL.z = fmaf(sw, __int_as_float(u.y << 16),         accL.z); \
        accL.w = fmaf(sw, __int_as_float(u.y & 0xFFFF0000u), accL.w); \
        accH.x = fmaf(sw, __int_as_float(u.z << 16),         accH.x); \
        accH.y = fmaf(sw, __int_as_float(u.z & 0xFFFF0000u), accH.y); \
        accH.z = fmaf(sw, __int_as_float(u.w << 16),         accH.z); \
        accH.w = fmaf(sw, __int_as_float(u.w & 0xFFFF0000u), accH.w); \
    } while (0)

    // double-buffered: batch A = k0..k0+3, batch B = next 4; <=8 loads in flight
    GLOAD(A0, wA0,  0); GLOAD(A1, wA1,  1); GLOAD(A2, wA2,  2); GLOAD(A3, wA3,  3);
    GLOAD(B0, wB0,  4); GLOAD(B1, wB1,  5); GLOAD(B2, wB2,  6); GLOAD(B3, wB3,  7);
    FMA8(A0, wA0); FMA8(A1, wA1); FMA8(A2, wA2); FMA8(A3, wA3);
    GLOAD(A0, wA0,  8); GLOAD(A1, wA1,  9); GLOAD(A2, wA2, 10); GLOAD(A3, wA3, 11);
    FMA8(B0, wB0); FMA8(B1, wB1); FMA8(B2, wB2); FMA8(B3, wB3);
    GLOAD(B0, wB0, 12); GLOAD(B1, wB1, 13); GLOAD(B2, wB2, 14); GLOAD(B3, wB3, 15);
    FMA8(A0, wA0); FMA8(A1, wA1); FMA8(A2, wA2); FMA8(A3, wA3);
    GLOAD(A0, wA0, 16); GLOAD(A1, wA1, 17); GLOAD(A2, wA2, 18); GLOAD(A3, wA3, 19);
    FMA8(B0, wB0); FMA8(B1, wB1); FMA8(B2, wB2); FMA8(B3, wB3);
    GLOAD(B0, wB0, 20); GLOAD(B1, wB1, 21); GLOAD(B2, wB2, 22); GLOAD(B3, wB3, 23);
    FMA8(A0, wA0); FMA8(A1, wA1); FMA8(A2, wA2); FMA8(A3, wA3);
    GLOAD(A0, wA0, 24); GLOAD(A1, wA1, 25); GLOAD(A2, wA2, 26); GLOAD(A3, wA3, 27);
    FMA8(B0, wB0); FMA8(B1, wB1); FMA8(B2, wB2); FMA8(B3, wB3);
    GLOAD(B0, wB0, 28); GLOAD(B1, wB1, 29); GLOAD(B2, wB2, 30); GLOAD(B3, wB3, 31);
    FMA8(A0, wA0); FMA8(A1, wA1); FMA8(A2, wA2); FMA8(A3, wA3);
    FMA8(B0, wB0); FMA8(B1, wB1); FMA8(B2, wB2); FMA8(B3, wB3);

#undef GLOAD
#undef FMA8

    const float bv = biasp[o];
    accL.x += bv; accL.y += bv; accL.z += bv; accL.w += bv;
    accH.x += bv; accH.y += bv; accH.z += bv; accH.w += bv;
    *(float4*)(&lds[wid][b8])     = accL;
    *(float4*)(&lds[wid][b8 + 4]) = accH;
    __syncthreads();

    // corner-turn write: 512 b x 8 o = 4096 floats, 2 passes of 2048
    #pragma unroll
    for (int p = 0; p < 2; ++p) {
        const int q = p * 2048 + t * 4;
        const int b = q >> 3;
        const int oo = q & 7;            // 0 or 4
        float4 v;
        v.x = lds[oo + 0][b];
        v.y = lds[oo + 1][b];
        v.z = lds[oo + 2][b];
        v.w = lds[oo + 3][b];
        *(float4*)(out + (size_t)b * OUT_DIM + o_blk + oo) = v;
    }
}

// ---------------------------------------------------------------------------
// Fallback (workspace too small): direct gather, correct but slow.
// ---------------------------------------------------------------------------
__global__ void sparse_fallback(const float* __restrict__ x,
                                const int*   __restrict__ idxp,
                                const float* __restrict__ wp,
                                const float* __restrict__ biasp,
                                float*       __restrict__ out) {
    const int i = blockIdx.x * blockDim.x + threadIdx.x;
    if (i >= B_DIM * OUT_DIM) return;
    const int b = i / OUT_DIM;
    const int o = i % OUT_DIM;
    float a = biasp[o];
    for (int k = 0; k < K_DIM; ++k) {
        const int idx = idxp[o * K_DIM + k];
        a = fmaf(wp[o * K_DIM + k], x[(size_t)b * IN_DIM + idx], a);
    }
    out[i] = a;
}

extern "C" void kernel_launch(void* const* d_in, const int* in_sizes, int n_in,
                              void* d_out, int out_size, void* d_ws, size_t ws_size,
                              hipStream_t stream) {
    const float* x       = (const float*)d_in[0];
    const int*   indices = (const int*)  d_in[1];
    const float* weight  = (const float*)d_in[2];
    const float* bias    = (const float*)d_in[3];
    float*       out     = (float*)d_out;

    const size_t need = (size_t)IN_DIM * B_DIM * sizeof(unsigned short);  // 64 MiB
    if (ws_size >= need) {
        unsigned short* xT = (unsigned short*)d_ws;
        transpose_bf16_k<<<IN_DIM / 32, 512, 0, stream>>>(x, xT);
        sparse_main<<<OUT_DIM / 8, 512, 0, stream>>>(xT, indices, weight, bias, out);
    } else {
        const int n = B_DIM * OUT_DIM;
        sparse_fallback<<<(n + 255) / 256, 256, 0, stream>>>(x, indices, weight, bias, out);
    }
}